// Round 5
// baseline (381.914 us; speedup 1.0000x reference)
//
#include <hip/hip_runtime.h>
#include <math.h>

#define B 8
#define S 2048
#define DM 1024
#define DK 64
#define M_ROWS (B*S)
#define DMS 128

typedef short s8v __attribute__((ext_vector_type(8)));     // 8 bf16 (4 VGPR)
typedef float f4v __attribute__((ext_vector_type(4)));     // 4 fp32
typedef unsigned short us4 __attribute__((ext_vector_type(4)));

__device__ __forceinline__ unsigned short f2bf(float f) {
    union { float f; unsigned u; } v; v.f = f;
    unsigned r = v.u + 0x7fffu + ((v.u >> 16) & 1u);   // RNE
    return (unsigned short)(r >> 16);
}
__device__ __forceinline__ s8v ld8(const unsigned short* p) {
    return *(const s8v*)p;
}
__device__ __forceinline__ f4v mf16(s8v a, s8v b, f4v c) {
    return __builtin_amdgcn_mfma_f32_16x16x32_bf16(a, b, c, 0, 0, 0);
}
__device__ __forceinline__ unsigned fbits(float f) {
    union { float f; unsigned u; } v; v.f = f; return v.u;
}

// ---------------- cast x (fp32 -> bf16) ----------------
__global__ __launch_bounds__(256) void cast_x(const float* __restrict__ x,
                                              unsigned short* __restrict__ xb) {
    size_t i = ((size_t)blockIdx.x * 256 + threadIdx.x) * 4;
    float4 v = *(const float4*)(x + i);
    us4 o; o.x = f2bf(v.x); o.y = f2bf(v.y); o.z = f2bf(v.z); o.w = f2bf(v.w);
    *(us4*)(xb + i) = o;
}

// ---------------- transpose + cast Wv -> Wvt[n][k] bf16 ----------------
__global__ __launch_bounds__(256) void wv_t(const float* __restrict__ Wv,
                                            unsigned short* __restrict__ Wvt) {
    __shared__ float T[32][33];
    int t = threadIdx.x;
    int k0 = blockIdx.y * 32, n0 = blockIdx.x * 32;
    int r = t >> 3, c = (t & 7) * 4;
    float4 v = *(const float4*)(Wv + (size_t)(k0 + r) * DM + n0 + c);
    T[r][c + 0] = v.x; T[r][c + 1] = v.y; T[r][c + 2] = v.z; T[r][c + 3] = v.w;
    __syncthreads();
    us4 o;
    o.x = f2bf(T[c + 0][r]); o.y = f2bf(T[c + 1][r]);
    o.z = f2bf(T[c + 2][r]); o.w = f2bf(T[c + 3][r]);
    *(us4*)(Wvt + (size_t)(n0 + r) * DM + k0 + c) = o;
}

// ---------------- transpose + cast Wq|Wk -> Wqkt[128][1024] bf16 ----------
__global__ __launch_bounds__(256) void wqk_t(const float* __restrict__ Wq,
                                             const float* __restrict__ Wk,
                                             unsigned short* __restrict__ Wqkt) {
    __shared__ float T[32][33];
    int t = threadIdx.x;
    int k0 = blockIdx.y * 32, n0 = blockIdx.x * 32;
    const float* src = (n0 < 64) ? Wq : Wk;
    int nc = (n0 < 64) ? n0 : (n0 - 64);
    int r = t >> 3, c = (t & 7) * 4;
    float4 v = *(const float4*)(src + (size_t)(k0 + r) * DK + nc + c);
    T[r][c + 0] = v.x; T[r][c + 1] = v.y; T[r][c + 2] = v.z; T[r][c + 3] = v.w;
    __syncthreads();
    us4 o;
    o.x = f2bf(T[c + 0][r]); o.y = f2bf(T[c + 1][r]);
    o.z = f2bf(T[c + 2][r]); o.w = f2bf(T[c + 3][r]);
    *(us4*)(Wqkt + (size_t)(n0 + r) * DM + k0 + c) = o;
}

// ---------------- Q/K projection: bf16 MFMA GEMM 16384x128x1024 ----------
// Q output prescaled by 0.125 * log2(e) so attn can use exp2 directly.
__global__ __launch_bounds__(256) void qk_mfma(
        const unsigned short* __restrict__ xb,
        const unsigned short* __restrict__ Wqkt,
        const float* __restrict__ bq, const float* __restrict__ bk,
        unsigned short* __restrict__ Q, unsigned short* __restrict__ Ko) {
    __shared__ unsigned short XS[64][72];
    __shared__ unsigned short WS[128][72];
    int t = threadIdx.x;
    int w = t >> 6, lane = t & 63, l16 = lane & 15, quad = lane >> 4;
    int m0 = blockIdx.x * 64;
    f4v acc[8] = {};
    int r = t >> 3, c = (t & 7) * 8;
    for (int k0 = 0; k0 < DM; k0 += 64) {
        __syncthreads();
        *(s8v*)&XS[r][c]      = ld8(xb + (size_t)(m0 + r) * DM + k0 + c);
        *(s8v*)&XS[r + 32][c] = ld8(xb + (size_t)(m0 + r + 32) * DM + k0 + c);
        #pragma unroll
        for (int i = 0; i < 4; ++i)
            *(s8v*)&WS[r + i * 32][c] = ld8(Wqkt + (size_t)(r + i * 32) * DM + k0 + c);
        __syncthreads();
        s8v a0 = *(const s8v*)&XS[w * 16 + l16][quad * 8];
        s8v a1 = *(const s8v*)&XS[w * 16 + l16][32 + quad * 8];
        #pragma unroll
        for (int nt = 0; nt < 8; ++nt) {
            s8v b0 = *(const s8v*)&WS[nt * 16 + l16][quad * 8];
            s8v b1 = *(const s8v*)&WS[nt * 16 + l16][32 + quad * 8];
            acc[nt] = mf16(a0, b0, acc[nt]);
            acc[nt] = mf16(a1, b1, acc[nt]);
        }
    }
    #pragma unroll
    for (int nt = 0; nt < 8; ++nt) {
        int n = nt * 16 + l16;
        float bias = (nt < 4) ? bq[n] : bk[n - 64];
        unsigned short* dst = (nt < 4) ? Q : Ko;
        float scale = (nt < 4) ? 0.18033688f : 1.0f;   // 0.125*log2(e)
        int nn = (nt < 4) ? n : (n - 64);
        #pragma unroll
        for (int rr = 0; rr < 4; ++rr) {
            int m = m0 + w * 16 + quad * 4 + rr;
            dst[(size_t)m * DK + nn] = f2bf((acc[nt][rr] + bias) * scale);
        }
    }
}

// ---------------- V projection: bf16 MFMA, writes Vt[b][n][s] bf16 --------
__global__ __launch_bounds__(256) void v_proj_mfma(
        const unsigned short* __restrict__ xb,
        const unsigned short* __restrict__ Wvt,
        const float* __restrict__ bv,
        unsigned short* __restrict__ Vt) {
    __shared__ unsigned short XS[128][40];
    __shared__ unsigned short WS[128][40];
    int t = threadIdx.x;
    int w = t >> 6, lane = t & 63, l16 = lane & 15, quad = lane >> 4;
    int m0 = blockIdx.y * 128, n0 = blockIdx.x * 128;
    int wm = (w >> 1) * 64, wn = (w & 1) * 64;
    f4v acc[4][4] = {};
    int rr = t >> 2, cc = (t & 3) * 8;
    for (int k0 = 0; k0 < DM; k0 += 32) {
        __syncthreads();
        *(s8v*)&XS[rr][cc]      = ld8(xb  + (size_t)(m0 + rr)      * DM + k0 + cc);
        *(s8v*)&XS[rr + 64][cc] = ld8(xb  + (size_t)(m0 + rr + 64) * DM + k0 + cc);
        *(s8v*)&WS[rr][cc]      = ld8(Wvt + (size_t)(n0 + rr)      * DM + k0 + cc);
        *(s8v*)&WS[rr + 64][cc] = ld8(Wvt + (size_t)(n0 + rr + 64) * DM + k0 + cc);
        __syncthreads();
        s8v af[4], bf[4];
        #pragma unroll
        for (int i = 0; i < 4; ++i) af[i] = *(const s8v*)&XS[wm + i * 16 + l16][quad * 8];
        #pragma unroll
        for (int j = 0; j < 4; ++j) bf[j] = *(const s8v*)&WS[wn + j * 16 + l16][quad * 8];
        #pragma unroll
        for (int i = 0; i < 4; ++i)
            #pragma unroll
            for (int j = 0; j < 4; ++j)
                acc[i][j] = mf16(af[i], bf[j], acc[i][j]);
    }
    int bb = m0 >> 11;
    #pragma unroll
    for (int j = 0; j < 4; ++j) {
        int n = n0 + wn + j * 16 + l16;
        float bias = bv[n];
        #pragma unroll
        for (int i = 0; i < 4; ++i) {
            int m = m0 + wm + i * 16 + quad * 4;
            int s = m & (S - 1);
            us4 o;
            o.x = f2bf(acc[i][j][0] + bias); o.y = f2bf(acc[i][j][1] + bias);
            o.z = f2bf(acc[i][j][2] + bias); o.w = f2bf(acc[i][j][3] + bias);
            *(us4*)(Vt + ((size_t)bb * DM + n) * S + s) = o;
        }
    }
}

// ---------------- MFMA flash attention v3 ----------------
// Block: 128 q-rows x 128 dm-slice, TK=64, 3 blocks/CU.
// Register-prefetched K/V staging; transposed QK^T (per-lane softmax rows,
// fixed m=0); exp2 with prescaled Q; v_perm P-packing; XOR-swizzled LDS.
__global__ __launch_bounds__(256, 3) void attn_mfma(
        const unsigned short* __restrict__ Q,   // prescaled by 0.125*log2e
        const unsigned short* __restrict__ K,
        const unsigned short* __restrict__ Vt,
        float* __restrict__ out) {
    __shared__ unsigned short KS[64][64];    // [j][d]
    __shared__ unsigned short VS[128][64];   // [n][j]
    __shared__ unsigned short PS[128][64];   // [q][j]
    __shared__ float lS[128];

    int t = threadIdx.x;
    int w = t >> 6, lane = t & 63;
    int l16 = lane & 15, hi = lane >> 4;     // hi in 0..3
    int b = blockIdx.z;
    int q0 = ((int)gridDim.y - 1 - (int)blockIdx.y) * 128;  // heavy blocks first
    int dm0 = blockIdx.x * DMS;
    int wn = w * 32;                         // wave's n-slice for PV
    int qw = q0 + w * 32;                    // wave's q-tile for QK/softmax

    // Q B-fragments (cols = q), persistent
    s8v qf[2][2];
    #pragma unroll
    for (int qh = 0; qh < 2; ++qh)
        #pragma unroll
        for (int ks = 0; ks < 2; ++ks)
            qf[qh][ks] = ld8(Q + ((size_t)b * S + qw + qh * 16 + l16) * DK + ks * 32 + hi * 8);

    float lacc[2] = {0.f, 0.f};
    f4v acc[8][2] = {};                      // [qt][nt]
    const int jend = q0 + 128;

    // prefetch registers for K (2 chunks) and V (4 chunks)
    s8v kpre[2], vpre[4];
    {
        #pragma unroll
        for (int rep = 0; rep < 2; ++rep) {
            int cid = rep * 256 + t, row = cid >> 3, c = cid & 7;
            kpre[rep] = ld8(K + ((size_t)b * S + row) * DK + c * 8);
        }
        #pragma unroll
        for (int rep = 0; rep < 4; ++rep) {
            int cid = rep * 256 + t, n = cid >> 3, c = cid & 7;
            vpre[rep] = ld8(Vt + ((size_t)b * DM + dm0 + n) * S + c * 8);
        }
    }

    for (int j0 = 0; j0 < jend; j0 += 64) {
        __syncthreads();
        // commit prefetched tiles to LDS (XOR-swizzled)
        #pragma unroll
        for (int rep = 0; rep < 2; ++rep) {
            int cid = rep * 256 + t, row = cid >> 3, c = cid & 7;
            *(s8v*)&KS[row][(c ^ (row & 7)) * 8] = kpre[rep];
        }
        #pragma unroll
        for (int rep = 0; rep < 4; ++rep) {
            int cid = rep * 256 + t, n = cid >> 3, c = cid & 7;
            *(s8v*)&VS[n][(c ^ (n & 7)) * 8] = vpre[rep];
        }
        __syncthreads();
        // issue prefetch for next tile (overlaps QK+PV compute)
        if (j0 + 64 < jend) {
            #pragma unroll
            for (int rep = 0; rep < 2; ++rep) {
                int cid = rep * 256 + t, row = cid >> 3, c = cid & 7;
                kpre[rep] = ld8(K + ((size_t)b * S + j0 + 64 + row) * DK + c * 8);
            }
            #pragma unroll
            for (int rep = 0; rep < 4; ++rep) {
                int cid = rep * 256 + t, n = cid >> 3, c = cid & 7;
                vpre[rep] = ld8(Vt + ((size_t)b * DM + dm0 + n) * S + j0 + 64 + c * 8);
            }
        }

        if (j0 <= qw + 31) {
            // QK^T (transposed): Sc^T[64j x 32q]
            bool nomask = (j0 + 63 <= qw);
            #pragma unroll
            for (int jt = 0; jt < 4; ++jt) {
                int jrow = jt * 16 + l16;
                s8v ka0 = *(const s8v*)&KS[jrow][((0 + hi) ^ (jrow & 7)) * 8];
                s8v ka1 = *(const s8v*)&KS[jrow][((4 + hi) ^ (jrow & 7)) * 8];
                #pragma unroll
                for (int qh = 0; qh < 2; ++qh) {
                    f4v d = {0.f, 0.f, 0.f, 0.f};
                    d = mf16(ka0, qf[qh][0], d);
                    d = mf16(ka1, qf[qh][1], d);
                    int qg = qw + qh * 16 + l16;
                    int jbase = j0 + jt * 16 + hi * 4;
                    float p0, p1, p2, p3;
                    if (nomask) {
                        p0 = exp2f(d[0]); p1 = exp2f(d[1]);
                        p2 = exp2f(d[2]); p3 = exp2f(d[3]);
                    } else {
                        p0 = (jbase + 0 <= qg) ? exp2f(d[0]) : 0.f;
                        p1 = (jbase + 1 <= qg) ? exp2f(d[1]) : 0.f;
                        p2 = (jbase + 2 <= qg) ? exp2f(d[2]) : 0.f;
                        p3 = (jbase + 3 <= qg) ? exp2f(d[3]) : 0.f;
                    }
                    lacc[qh] += (p0 + p1) + (p2 + p3);
                    // pack 4 fp32 -> 4 bf16 (truncate) with 2 v_perm
                    uint2 pk;
                    pk.x = __builtin_amdgcn_perm(fbits(p1), fbits(p0), 0x07060302u);
                    pk.y = __builtin_amdgcn_perm(fbits(p3), fbits(p2), 0x07060302u);
                    int prow = w * 32 + qh * 16 + l16;
                    int pc = jt * 2 + (hi >> 1);
                    *(uint2*)&PS[prow][((pc ^ (prow & 7)) * 8) + (hi & 1) * 4] = pk;
                }
            }
        } else {
            // fully-masked wave-tile: just zero own P rows
            uint2 z = {0u, 0u};
            #pragma unroll
            for (int jt = 0; jt < 4; ++jt)
                #pragma unroll
                for (int qh = 0; qh < 2; ++qh) {
                    int prow = w * 32 + qh * 16 + l16;
                    int pc = jt * 2 + (hi >> 1);
                    *(uint2*)&PS[prow][((pc ^ (prow & 7)) * 8) + (hi & 1) * 4] = z;
                }
        }
        __syncthreads();

        // PV: O[128q x 32n(wave slice)] += P(128x64) . V(64x32 slice)
        #pragma unroll
        for (int js = 0; js < 2; ++js) {
            s8v pa[8];
            #pragma unroll
            for (int qt = 0; qt < 8; ++qt) {
                int qr = qt * 16 + l16;
                pa[qt] = *(const s8v*)&PS[qr][((js * 4 + hi) ^ (qr & 7)) * 8];
            }
            #pragma unroll
            for (int nt = 0; nt < 2; ++nt) {
                int nr = wn + nt * 16 + l16;
                s8v vb = *(const s8v*)&VS[nr][((js * 4 + hi) ^ (nr & 7)) * 8];
                #pragma unroll
                for (int qt = 0; qt < 8; ++qt)
                    acc[qt][nt] = mf16(pa[qt], vb, acc[qt][nt]);
            }
        }
    }

    // denominators: lanes (l16,qh) share q across hi -> reduce over hi
    #pragma unroll
    for (int qh = 0; qh < 2; ++qh) {
        float lt = lacc[qh];
        lt += __shfl_xor(lt, 16);
        lt += __shfl_xor(lt, 32);
        if (hi == 0) lS[w * 32 + qh * 16 + l16] = lt;
    }
    __syncthreads();

    // epilogue: normalize + store fp32
    #pragma unroll
    for (int qt = 0; qt < 8; ++qt) {
        f4v lv = *(const f4v*)&lS[qt * 16 + hi * 4];
        f4v inv;
        inv[0] = 1.f / lv[0]; inv[1] = 1.f / lv[1];
        inv[2] = 1.f / lv[2]; inv[3] = 1.f / lv[3];
        size_t rbase = (size_t)b * S + q0 + qt * 16 + hi * 4;
        #pragma unroll
        for (int nt = 0; nt < 2; ++nt)
            #pragma unroll
            for (int r = 0; r < 4; ++r)
                out[(rbase + r) * DM + dm0 + wn + nt * 16 + l16] = acc[qt][nt][r] * inv[r];
    }
}

extern "C" void kernel_launch(void* const* d_in, const int* in_sizes, int n_in,
                              void* d_out, int out_size, void* d_ws, size_t ws_size,
                              hipStream_t stream) {
    const float* x  = (const float*)d_in[0];
    const float* Wq = (const float*)d_in[1];
    const float* bq = (const float*)d_in[2];
    const float* Wk = (const float*)d_in[3];
    const float* bk = (const float*)d_in[4];
    const float* Wv = (const float*)d_in[5];
    const float* bv = (const float*)d_in[6];
    float* out = (float*)d_out;

    unsigned short* xb   = (unsigned short*)d_ws;                // 16384x1024
    unsigned short* Wvt  = xb   + (size_t)M_ROWS * DM;           // 1024x1024
    unsigned short* Qb   = Wvt  + (size_t)DM * DM;               // 16384x64
    unsigned short* Kb   = Qb   + (size_t)M_ROWS * DK;           // 16384x64
    unsigned short* Vt   = Kb   + (size_t)M_ROWS * DK;           // 8x1024x2048
    unsigned short* Wqkt = Vt   + (size_t)B * DM * S;            // 128x1024

    cast_x<<<(size_t)M_ROWS * DM / 1024, 256, 0, stream>>>(x, xb);
    wv_t<<<dim3(32, 32), 256, 0, stream>>>(Wv, Wvt);
    wqk_t<<<dim3(4, 32), 256, 0, stream>>>(Wq, Wk, Wqkt);
    qk_mfma<<<M_ROWS / 64, 256, 0, stream>>>(xb, Wqkt, bq, bk, Qb, Kb);
    v_proj_mfma<<<dim3(DM / 128, M_ROWS / 128), 256, 0, stream>>>(xb, Wvt, bv, Vt);
    attn_mfma<<<dim3(DM / DMS, S / 128, B), 256, 0, stream>>>(Qb, Kb, Vt, out);
}